// Round 9
// baseline (463.133 us; speedup 1.0000x reference)
//
#include <hip/hip_runtime.h>
#include <cstdint>

typedef unsigned int uint;
typedef unsigned short ushort_t;
typedef unsigned long long ull;
typedef __attribute__((ext_vector_type(8))) short bf16x8;
typedef __attribute__((ext_vector_type(4))) float f32x4;
typedef __attribute__((ext_vector_type(2))) float f32x2;

#define B_   16
#define N_   2048
#define S_   512
#define G_   8192       // B_*S_
#define DIN  64
#define DOUT 128
#define K_   32
#define ATS  136        // gemm2 actT row stride (bf16)
#define ATS1 72         // gemm1 xgT row stride (bf16)

__device__ __forceinline__ uint bf16b(float f) {
  uint u = __float_as_uint(f);
  return (u + 0x7fffu + ((u >> 16) & 1u)) >> 16;
}
__device__ __forceinline__ float bf2f(uint b) { return __uint_as_float(b << 16); }

template<int CTRL, int RM>
__device__ __forceinline__ float dpp_fmax_step(float x) {
  float y = __uint_as_float((uint)__builtin_amdgcn_update_dpp(
      (int)__float_as_uint(x), (int)__float_as_uint(x), CTRL, RM, 0xf, true));
  return fmaxf(x, y);   // bound_ctrl zero-fill: dists >= 0 -> identity for max
}

// ---------------- FPS: one block/batch, 4 waves x 8 pts/lane, exact fp32 ----------
// pk-pair update; value-only DPP max -> ballot/ffs resolve. Winner coords computed
// per-lane via 21-op cndmask tree (overlaps DPP, uniform control flow), broadcast by
// 3 readlanes; lane0 ships {key, float4 coords} -> ONE post-barrier LDS round
// (4 keys + 4 float4 issued together). Ref scan emits PRE-update far.
__global__ __launch_bounds__(256) void fps_kernel(const float* __restrict__ coords,
                                                  int* __restrict__ fidx,
                                                  float* __restrict__ out_xyz) {
  int b = blockIdx.x;
  const float* cb = coords + (size_t)b * (N_ * 3);
  __shared__ float sptx[N_], spty[N_], sptz[N_];
  __shared__ ull    skey[2][4];
  __shared__ float4 scand[2][4];
  __shared__ int    sfar[S_];
  int tid = threadIdx.x, lane = tid & 63, wid = tid >> 6;
  for (int j = tid; j < N_; j += 256) {
    sptx[j] = cb[3 * j]; spty[j] = cb[3 * j + 1]; sptz[j] = cb[3 * j + 2];
  }
  f32x2 px[4], py[4], pz[4], dist[4];
  int j0 = tid * 8;
#pragma unroll
  for (int p = 0; p < 4; ++p) {
    int j = j0 + 2 * p;
    px[p].x = cb[3 * j];     py[p].x = cb[3 * j + 1]; pz[p].x = cb[3 * j + 2];
    px[p].y = cb[3 * j + 3]; py[p].y = cb[3 * j + 4]; pz[p].y = cb[3 * j + 5];
    dist[p].x = 1e10f; dist[p].y = 1e10f;
  }
  float cx = cb[0], cy = cb[1], cz = cb[2];
  uint far = 0;
  __syncthreads();
  for (int s = 0; s < S_; ++s) {
    if (tid == 0) sfar[s] = (int)far;          // PRE-update far (matches jax scan)
    f32x2 c2x = {cx, cx}, c2y = {cy, cy}, c2z = {cz, cz};
    float bestv = -1.f; uint bestloc = 0;
#pragma unroll
    for (int p = 0; p < 4; ++p) {
      f32x2 dx, dy, dz, qx, qy, qz, s1, s2;
      asm("v_pk_add_f32 %0, %1, %2 neg_lo:[0,1] neg_hi:[0,1]" : "=v"(dx) : "v"(px[p]), "v"(c2x));
      asm("v_pk_add_f32 %0, %1, %2 neg_lo:[0,1] neg_hi:[0,1]" : "=v"(dy) : "v"(py[p]), "v"(c2y));
      asm("v_pk_add_f32 %0, %1, %2 neg_lo:[0,1] neg_hi:[0,1]" : "=v"(dz) : "v"(pz[p]), "v"(c2z));
      asm("v_pk_mul_f32 %0, %1, %1" : "=v"(qx) : "v"(dx));
      asm("v_pk_mul_f32 %0, %1, %1" : "=v"(qy) : "v"(dy));
      asm("v_pk_mul_f32 %0, %1, %1" : "=v"(qz) : "v"(dz));
      asm("v_pk_add_f32 %0, %1, %2" : "=v"(s1) : "v"(qx), "v"(qy));
      asm("v_pk_add_f32 %0, %1, %2" : "=v"(s2) : "v"(s1), "v"(qz));
      float n0 = fminf(dist[p].x, s2.x);
      float n1 = fminf(dist[p].y, s2.y);
      dist[p].x = n0; dist[p].y = n1;
      bool g0 = n0 > bestv; bestv = g0 ? n0 : bestv; bestloc = g0 ? (uint)(2 * p) : bestloc;
      bool g1 = n1 > bestv; bestv = g1 ? n1 : bestv; bestloc = g1 ? (uint)(2 * p + 1) : bestloc;
    }
    // per-lane candidate coords (static 7-op tree per coord; overlaps DPP chain)
    bool h = (bestloc & 1u) != 0, qb0 = (bestloc & 2u) != 0, qb1 = (bestloc & 4u) != 0;
    float ax0 = h ? px[0].y : px[0].x, ax1 = h ? px[1].y : px[1].x;
    float ax2 = h ? px[2].y : px[2].x, ax3 = h ? px[3].y : px[3].x;
    float bx = qb1 ? (qb0 ? ax3 : ax2) : (qb0 ? ax1 : ax0);
    float ay0 = h ? py[0].y : py[0].x, ay1 = h ? py[1].y : py[1].x;
    float ay2 = h ? py[2].y : py[2].x, ay3 = h ? py[3].y : py[3].x;
    float by = qb1 ? (qb0 ? ay3 : ay2) : (qb0 ? ay1 : ay0);
    float az0 = h ? pz[0].y : pz[0].x, az1 = h ? pz[1].y : pz[1].x;
    float az2 = h ? pz[2].y : pz[2].x, az3 = h ? pz[3].y : pz[3].x;
    float bz = qb1 ? (qb0 ? az3 : az2) : (qb0 ? az1 : az0);
    // wave64 value-max (6 dpp+max, lands full in lane 63)
    float m = bestv;
    m = dpp_fmax_step<0x111, 0xf>(m);   // row_shr:1
    m = dpp_fmax_step<0x112, 0xf>(m);   // row_shr:2
    m = dpp_fmax_step<0x114, 0xf>(m);   // row_shr:4
    m = dpp_fmax_step<0x118, 0xf>(m);   // row_shr:8
    m = dpp_fmax_step<0x142, 0xa>(m);   // row_bcast:15 -> rows 1,3
    m = dpp_fmax_step<0x143, 0xc>(m);   // row_bcast:31 -> rows 2,3
    float wmax = __uint_as_float((uint)__builtin_amdgcn_readlane((int)__float_as_uint(m), 63));
    ull mask = __ballot(bestv == wmax);
    int wl = __ffsll((long long)mask) - 1;            // first lane = smallest j
    uint loc = (uint)__builtin_amdgcn_readlane((int)bestloc, wl);
    float wx = __uint_as_float((uint)__builtin_amdgcn_readlane((int)__float_as_uint(bx), wl));
    float wy = __uint_as_float((uint)__builtin_amdgcn_readlane((int)__float_as_uint(by), wl));
    float wz = __uint_as_float((uint)__builtin_amdgcn_readlane((int)__float_as_uint(bz), wl));
    uint jg = (uint)(((wid << 6) + wl) * 8) + loc;    // wave-winner global index
    int pb = s & 1;
    if (lane == 0) {
      skey[pb][wid] = ((ull)__float_as_uint(wmax) << 32) | (ull)(~jg);
      scand[pb][wid] = make_float4(wx, wy, wz, 0.f);
    }
    __syncthreads();                                  // lgkm-only barrier
    ull k0 = skey[pb][0], k1 = skey[pb][1], k2 = skey[pb][2], k3 = skey[pb][3];
    float4 q0 = scand[pb][0], q1 = scand[pb][1], q2 = scand[pb][2], q3 = scand[pb][3];
    bool t01 = k0 > k1, t23 = k2 > k3;
    ull ka = t01 ? k0 : k1;   float4 qa = t01 ? q0 : q1;
    ull kb2 = t23 ? k2 : k3;  float4 qb4 = t23 ? q2 : q3;
    bool tw = ka > kb2;
    far = ~(uint)(tw ? ka : kb2);
    float4 qw = tw ? qa : qb4;
    cx = qw.x; cy = qw.y; cz = qw.z;
  }
  __syncthreads();
  for (int s2 = tid; s2 < S_; s2 += 256) {
    int f = sfar[s2];
    fidx[b * S_ + s2] = f;
    int o = (b * S_ + s2) * 3;
    out_xyz[o] = sptx[f]; out_xyz[o + 1] = spty[f]; out_xyz[o + 2] = sptz[f];
  }
}

// ---------------- prep: B-fragment packs for both GEMMs ----------------
__global__ __launch_bounds__(256) void prep_kernel(const float* __restrict__ W1,
                                                   const float* __restrict__ W2,
                                                   ushort_t* __restrict__ Bp1,
                                                   ushort_t* __restrict__ Bpd,
                                                   ushort_t* __restrict__ Bp2) {
  int i = blockIdx.x * 256 + threadIdx.x;   // 16384
  int j2 = i & 7, l = (i >> 3) & 63;
  {
    int kc = (i >> 9) & 3, nt = i >> 11;
    int o2 = nt * 16 + (l & 15);
    int c2 = kc * 32 + ((l >> 4) * 8) + j2;
    Bp2[i] = (ushort_t)bf16b(W2[o2 * 128 + c2]);
  }
  if (i < 8192) {
    int kc = (i >> 9) & 1, nt = (i >> 10) & 7;
    int o2 = nt * 16 + (l & 15);
    int c2 = kc * 32 + ((l >> 4) * 8) + j2;
    float wa = W1[o2 * 128 + c2];
    float wb = W1[o2 * 128 + 64 + c2];
    Bp1[i] = (ushort_t)bf16b(wa);
    Bpd[i] = (ushort_t)bf16b(wb - wa);
  }
}

// ---------------- GEMM1 (MFMA bf16) + inline ball query ----------------
// Per wave: ball query (ballot prefix-count, early exit) -> sgidx in LDS, then
// h1T[g][k][o] = W1a@xg + (W1b-W1a)@ctr, CT layout D[m=k][n=o], per-o stats.
__global__ __launch_bounds__(256) void gemm1_kernel(const float* __restrict__ x,
    const float* __restrict__ coords, const int* __restrict__ fidx,
    const ushort_t* __restrict__ Bp1, const ushort_t* __restrict__ Bpd,
    ushort_t* __restrict__ h1T, float* __restrict__ psum, float* __restrict__ psq) {
  __shared__ ushort_t xgT[4][32 * ATS1];
  __shared__ float sctr[4][DIN];
  __shared__ int sgidx[4][K_];
  int tid = threadIdx.x;
  int lane = tid & 63, wid = tid >> 6;
  int g = __builtin_amdgcn_readfirstlane(blockIdx.x * 4 + wid);
  int b = g >> 9;
  const float* xb = x + (size_t)b * (DIN * N_);
  const float* cb = coords + (size_t)b * (N_ * 3);
  int nf = fidx[g];
  // ---- inline ball query (exact fp32, first-32 within radius, pad with first) ----
  {
    float cx = cb[3 * nf], cy = cb[3 * nf + 1], cz = cb[3 * nf + 2];
    int cnt = 0, first = 0;
    bool hasfirst = false;
    for (int base = 0; base < N_; base += 64) {
      int j = base + lane;
      float dx = __fsub_rn(cb[3 * j], cx);
      float dy = __fsub_rn(cb[3 * j + 1], cy);
      float dz = __fsub_rn(cb[3 * j + 2], cz);
      float d = __fadd_rn(__fadd_rn(__fmul_rn(dx, dx), __fmul_rn(dy, dy)), __fmul_rn(dz, dz));
      bool in = (d <= 0.25f);
      ull m = __ballot(in);
      if (in) {
        int pos = cnt + __popcll(m & ((1ull << lane) - 1ull));
        if (pos < K_) sgidx[wid][pos] = j;
      }
      if (!hasfirst && m) { first = base + (__ffsll((long long)m) - 1); hasfirst = true; }
      cnt += __popcll(m);
      if (cnt >= K_) break;
    }
    if (cnt < K_) {
      for (int p = cnt + lane; p < K_; p += 64) sgidx[wid][p] = first;
    }
  }
  sctr[wid][lane] = xb[(size_t)lane * N_ + nf];   // lane = c (0..63)
  int kk = lane & 31, ch = lane >> 5;
  int gik = sgidx[wid][kk];                        // same-wave LDS dependency
  ushort_t* xw = xgT[wid];
#pragma unroll
  for (int cc = 0; cc < 32; ++cc) {
    int c = ch * 32 + cc;
    xw[kk * ATS1 + c] = (ushort_t)bf16b(xb[(size_t)c * N_ + gik]);
  }
  __syncthreads();
  int l15 = lane & 15, r8 = (lane >> 4) * 8;
  f32x4 acc[2][8];
#pragma unroll
  for (int nt = 0; nt < 8; ++nt) acc[0][nt] = (f32x4){0.f, 0.f, 0.f, 0.f};
#pragma unroll
  for (int kc = 0; kc < 2; ++kc) {
    union { bf16x8 v; ushort_t u[8]; } cu;
#pragma unroll
    for (int j = 0; j < 8; ++j) cu.u[j] = (ushort_t)bf16b(sctr[wid][kc * 32 + r8 + j]);
#pragma unroll
    for (int nt = 0; nt < 8; ++nt) {
      bf16x8 bf = *(const bf16x8*)(Bpd + ((nt * 2 + kc) * 64 + lane) * 8);
      acc[0][nt] = __builtin_amdgcn_mfma_f32_16x16x32_bf16(cu.v, bf, acc[0][nt], 0, 0, 0);
    }
  }
#pragma unroll
  for (int nt = 0; nt < 8; ++nt) acc[1][nt] = acc[0][nt];
#pragma unroll
  for (int kc = 0; kc < 2; ++kc) {
    bf16x8 afrag[2];
#pragma unroll
    for (int mt = 0; mt < 2; ++mt)
      afrag[mt] = *(const bf16x8*)(xw + (mt * 16 + l15) * ATS1 + kc * 32 + r8);
#pragma unroll
    for (int nt = 0; nt < 8; ++nt) {
      bf16x8 bf = *(const bf16x8*)(Bp1 + ((nt * 2 + kc) * 64 + lane) * 8);
      acc[0][nt] = __builtin_amdgcn_mfma_f32_16x16x32_bf16(afrag[0], bf, acc[0][nt], 0, 0, 0);
      acc[1][nt] = __builtin_amdgcn_mfma_f32_16x16x32_bf16(afrag[1], bf, acc[1][nt], 0, 0, 0);
    }
  }
#pragma unroll
  for (int nt = 0; nt < 8; ++nt) {
    float s = 0.f, q = 0.f;
#pragma unroll
    for (int mt = 0; mt < 2; ++mt)
#pragma unroll
      for (int r = 0; r < 4; ++r) { float a = acc[mt][nt][r]; s += a; q = fmaf(a, a, q); }
    s += __shfl_xor(s, 16, 64); s += __shfl_xor(s, 32, 64);
    q += __shfl_xor(q, 16, 64); q += __shfl_xor(q, 32, 64);
    if (lane < 16) {
      int o = nt * 16 + lane;
      psum[o * G_ + g] = s; psq[o * G_ + g] = q;
    }
  }
#pragma unroll
  for (int mt = 0; mt < 2; ++mt)
#pragma unroll
    for (int r = 0; r < 4; ++r) {
      int k = mt * 16 + (lane >> 4) * 4 + r;
      ushort_t* dst = h1T + (size_t)g * 4096 + k * 128 + l15;
#pragma unroll
      for (int nt = 0; nt < 8; ++nt)
        dst[nt * 16] = (ushort_t)bf16b(acc[mt][nt][r]);
    }
}

// ---------------- BN finalize: per-channel mean/var -> scale/shift ----------------
__global__ __launch_bounds__(256) void bn_finalize(const float* __restrict__ psum,
    const float* __restrict__ psq, const float* __restrict__ gamma,
    const float* __restrict__ beta, float* __restrict__ bnp) {
  int o = blockIdx.x, tid = threadIdx.x;
  double s = 0.0, q = 0.0;
  for (int g = tid; g < G_; g += 256) { s += (double)psum[o * G_ + g]; q += (double)psq[o * G_ + g]; }
  __shared__ double ss[256], qq[256];
  ss[tid] = s; qq[tid] = q; __syncthreads();
  for (int off = 128; off > 0; off >>= 1) {
    if (tid < off) { ss[tid] += ss[tid + off]; qq[tid] += qq[tid + off]; }
    __syncthreads();
  }
  if (tid == 0) {
    double n = 262144.0;
    double mean = ss[0] / n, var = qq[0] / n - mean * mean;
    float scv = (float)((double)gamma[o] / sqrt(var + 1e-5));
    bnp[2 * o] = scv;
    bnp[2 * o + 1] = (float)((double)beta[o] - mean * (double)scv);
  }
}

// ---------------- GEMM2 (MFMA bf16): CT layout D[k][o], per-(g,o) stats ----------
__global__ __launch_bounds__(256) void gemm2_kernel(const ushort_t* __restrict__ h1T,
    const ushort_t* __restrict__ Bp2, const float* __restrict__ bnp1,
    float* __restrict__ psum, float* __restrict__ psq,
    float* __restrict__ hmax, float* __restrict__ hmin) {
  __shared__ ushort_t actT[4][32 * ATS];
  int tid = threadIdx.x;
  int lane = tid & 63, wid = tid >> 6;
  int g = __builtin_amdgcn_readfirstlane(blockIdx.x * 4 + wid);
  ushort_t* aw = actT[wid];
  int c0 = (lane & 15) * 8;
  float s1[8], t1[8];
#pragma unroll
  for (int jj = 0; jj < 8; ++jj) { s1[jj] = bnp1[2 * (c0 + jj)]; t1[jj] = bnp1[2 * (c0 + jj) + 1]; }
  const uint4* src = (const uint4*)(h1T + (size_t)g * 4096);
#pragma unroll
  for (int t = 0; t < 8; ++t) {
    int idx = t * 64 + lane;
    uint4 v = src[idx];
    int k = idx >> 4;
    uint w[4] = {v.x, v.y, v.z, v.w};
    uint o4[4];
#pragma unroll
    for (int p2 = 0; p2 < 4; ++p2) {
      float a0 = fmaxf(fmaf(bf2f(w[p2] & 0xffffu), s1[2 * p2], t1[2 * p2]), 0.f);
      float a1 = fmaxf(fmaf(bf2f(w[p2] >> 16), s1[2 * p2 + 1], t1[2 * p2 + 1]), 0.f);
      o4[p2] = (bf16b(a1) << 16) | bf16b(a0);
    }
    *(uint4*)(aw + k * ATS + c0) = make_uint4(o4[0], o4[1], o4[2], o4[3]);
  }
  __syncthreads();
  f32x4 acc[2][8];
#pragma unroll
  for (int mt = 0; mt < 2; ++mt)
#pragma unroll
    for (int nt = 0; nt < 8; ++nt) acc[mt][nt] = (f32x4){0.f, 0.f, 0.f, 0.f};
#pragma unroll
  for (int kc = 0; kc < 4; ++kc) {
    bf16x8 afrag[2];
#pragma unroll
    for (int mt = 0; mt < 2; ++mt)
      afrag[mt] = *(const bf16x8*)(aw + (mt * 16 + (lane & 15)) * ATS + kc * 32 + (lane >> 4) * 8);
#pragma unroll
    for (int nt = 0; nt < 8; ++nt) {
      bf16x8 bfrag = *(const bf16x8*)(Bp2 + ((nt * 4 + kc) * 64 + lane) * 8);
      acc[0][nt] = __builtin_amdgcn_mfma_f32_16x16x32_bf16(afrag[0], bfrag, acc[0][nt], 0, 0, 0);
      acc[1][nt] = __builtin_amdgcn_mfma_f32_16x16x32_bf16(afrag[1], bfrag, acc[1][nt], 0, 0, 0);
    }
  }
#pragma unroll
  for (int nt = 0; nt < 8; ++nt) {
    float s = 0.f, q = 0.f, mx = -1e30f, mn = 1e30f;
#pragma unroll
    for (int mt = 0; mt < 2; ++mt)
#pragma unroll
      for (int r = 0; r < 4; ++r) {
        float a = acc[mt][nt][r];
        s += a; q = fmaf(a, a, q); mx = fmaxf(mx, a); mn = fminf(mn, a);
      }
    s += __shfl_xor(s, 16, 64); s += __shfl_xor(s, 32, 64);
    q += __shfl_xor(q, 16, 64); q += __shfl_xor(q, 32, 64);
    mx = fmaxf(mx, __shfl_xor(mx, 16, 64)); mx = fmaxf(mx, __shfl_xor(mx, 32, 64));
    mn = fminf(mn, __shfl_xor(mn, 16, 64)); mn = fminf(mn, __shfl_xor(mn, 32, 64));
    if (lane < 16) {
      int o = nt * 16 + lane;
      psum[o * G_ + g] = s; psq[o * G_ + g] = q;
      hmax[o * G_ + g] = mx; hmin[o * G_ + g] = mn;
    }
  }
}

// ---------------- pool: out[b,o,s] = relu(s2 * (s2>=0 ? max : min) + t2) ----------------
__global__ __launch_bounds__(256) void pool_kernel(const float* __restrict__ hmax,
    const float* __restrict__ hmin, const float* __restrict__ bnp2,
    float* __restrict__ out) {
  int i = blockIdx.x * 256 + threadIdx.x;   // 1,048,576 = (b*128+o)*512+s
  int s = i & 511;
  int o = (i >> 9) & 127;
  int b = i >> 16;
  int g = b * 512 + s;
  float scv = bnp2[2 * o], tf = bnp2[2 * o + 1];
  float v = (scv >= 0.f) ? hmax[o * G_ + g] : hmin[o * G_ + g];
  out[i] = fmaxf(fmaf(scv, v, tf), 0.f);
}

extern "C" void kernel_launch(void* const* d_in, const int* in_sizes, int n_in,
                              void* d_out, int out_size, void* d_ws, size_t ws_size,
                              hipStream_t stream) {
  const float* x      = (const float*)d_in[0];
  const float* coords = (const float*)d_in[1];
  const float* W1     = (const float*)d_in[2];
  const float* W2     = (const float*)d_in[3];
  const float* gamma1 = (const float*)d_in[4];
  const float* beta1  = (const float*)d_in[5];
  const float* gamma2 = (const float*)d_in[6];
  const float* beta2  = (const float*)d_in[7];
  float* out = (float*)d_out;
  char* ws = (char*)d_ws;
  ushort_t* h1T  = (ushort_t*)(ws);               // 67,108,864 B  (h1T[g][k][o] bf16)
  float* psum1 = (float*)(ws + 67108864);         // 4 MB each below
  float* psq1  = (float*)(ws + 71303168);
  float* psum2 = (float*)(ws + 75497472);
  float* psq2  = (float*)(ws + 79691776);
  float* hmax  = (float*)(ws + 83886080);
  float* hmin  = (float*)(ws + 88080384);
  ushort_t* Bp1 = (ushort_t*)(ws + 92274688);     // 16 KB
  ushort_t* Bpd = (ushort_t*)(ws + 92291072);     // 16 KB
  ushort_t* Bp2 = (ushort_t*)(ws + 92307456);     // 32 KB
  float* bnp1  = (float*)(ws + 92340224);
  float* bnp2  = (float*)(ws + 92341248);
  int* fidx    = (int*)(ws + 92342272);           // 32 KB, end 92,375,040 B

  prep_kernel<<<64, 256, 0, stream>>>(W1, W2, Bp1, Bpd, Bp2);
  fps_kernel<<<16, 256, 0, stream>>>(coords, fidx, out);
  gemm1_kernel<<<2048, 256, 0, stream>>>(x, coords, fidx, Bp1, Bpd, h1T, psum1, psq1);
  bn_finalize<<<128, 256, 0, stream>>>(psum1, psq1, gamma1, beta1, bnp1);
  gemm2_kernel<<<2048, 256, 0, stream>>>(h1T, Bp2, bnp1, psum2, psq2, hmax, hmin);
  bn_finalize<<<128, 256, 0, stream>>>(psum2, psq2, gamma2, beta2, bnp2);
  pool_kernel<<<4096, 256, 0, stream>>>(hmax, hmin, bnp2, out + 24576);
}

// Round 10
// 354.889 us; speedup vs baseline: 1.3050x; 1.3050x over previous
//
#include <hip/hip_runtime.h>
#include <cstdint>

typedef unsigned int uint;
typedef unsigned short ushort_t;
typedef unsigned long long ull;
typedef __attribute__((ext_vector_type(8))) short bf16x8;
typedef __attribute__((ext_vector_type(4))) float f32x4;
typedef __attribute__((ext_vector_type(2))) float f32x2;

#define B_   16
#define N_   2048
#define S_   512
#define G_   8192       // B_*S_
#define DIN  64
#define DOUT 128
#define K_   32
#define ATS  136        // gemm2 actT row stride (bf16)

__device__ __forceinline__ uint bf16b(float f) {
  uint u = __float_as_uint(f);
  return (u + 0x7fffu + ((u >> 16) & 1u)) >> 16;
}
__device__ __forceinline__ float bf2f(uint b) { return __uint_as_float(b << 16); }

template<int CTRL, int RM>
__device__ __forceinline__ float dpp_fmax_step(float x) {
  float y = __uint_as_float((uint)__builtin_amdgcn_update_dpp(
      (int)__float_as_uint(x), (int)__float_as_uint(x), CTRL, RM, 0xf, true));
  return fmaxf(x, y);   // bound_ctrl zero-fill: dists >= 0 -> identity for max
}

// ---------------- FPS (R8-proven, 228us): 4 waves x 8 pts/lane, exact fp32 --------
// pk-pair update; value-only DPP max -> ballot/ffs resolve; lane0 ships 8B key only;
// post-barrier: 4 keys + 12 speculative broadcast coord reads overlap the key tree.
// Reference scan emits PRE-update far (idx[0]==0) -> record at loop top.
__global__ __launch_bounds__(256) void fps_kernel(const float* __restrict__ coords,
                                                  int* __restrict__ fidx,
                                                  float* __restrict__ out_xyz) {
  int b = blockIdx.x;
  const float* cb = coords + (size_t)b * (N_ * 3);
  __shared__ float sptx[N_], spty[N_], sptz[N_];
  __shared__ ull   skey[2][4];
  __shared__ int   sfar[S_];
  int tid = threadIdx.x, lane = tid & 63, wid = tid >> 6;
  for (int j = tid; j < N_; j += 256) {
    sptx[j] = cb[3 * j]; spty[j] = cb[3 * j + 1]; sptz[j] = cb[3 * j + 2];
  }
  f32x2 px[4], py[4], pz[4], dist[4];
  int j0 = tid * 8;
#pragma unroll
  for (int p = 0; p < 4; ++p) {
    int j = j0 + 2 * p;
    px[p].x = cb[3 * j];     py[p].x = cb[3 * j + 1]; pz[p].x = cb[3 * j + 2];
    px[p].y = cb[3 * j + 3]; py[p].y = cb[3 * j + 4]; pz[p].y = cb[3 * j + 5];
    dist[p].x = 1e10f; dist[p].y = 1e10f;
  }
  float cx = cb[0], cy = cb[1], cz = cb[2];
  uint far = 0;
  __syncthreads();
  for (int s = 0; s < S_; ++s) {
    if (tid == 0) sfar[s] = (int)far;          // PRE-update far (matches jax scan)
    f32x2 c2x = {cx, cx}, c2y = {cy, cy}, c2z = {cz, cz};
    float bestv = -1.f; uint bestloc = 0;
#pragma unroll
    for (int p = 0; p < 4; ++p) {
      f32x2 dx, dy, dz, qx, qy, qz, s1, s2;
      asm("v_pk_add_f32 %0, %1, %2 neg_lo:[0,1] neg_hi:[0,1]" : "=v"(dx) : "v"(px[p]), "v"(c2x));
      asm("v_pk_add_f32 %0, %1, %2 neg_lo:[0,1] neg_hi:[0,1]" : "=v"(dy) : "v"(py[p]), "v"(c2y));
      asm("v_pk_add_f32 %0, %1, %2 neg_lo:[0,1] neg_hi:[0,1]" : "=v"(dz) : "v"(pz[p]), "v"(c2z));
      asm("v_pk_mul_f32 %0, %1, %1" : "=v"(qx) : "v"(dx));
      asm("v_pk_mul_f32 %0, %1, %1" : "=v"(qy) : "v"(dy));
      asm("v_pk_mul_f32 %0, %1, %1" : "=v"(qz) : "v"(dz));
      asm("v_pk_add_f32 %0, %1, %2" : "=v"(s1) : "v"(qx), "v"(qy));
      asm("v_pk_add_f32 %0, %1, %2" : "=v"(s2) : "v"(s1), "v"(qz));
      float n0 = fminf(dist[p].x, s2.x);
      float n1 = fminf(dist[p].y, s2.y);
      dist[p].x = n0; dist[p].y = n1;
      bool g0 = n0 > bestv; bestv = g0 ? n0 : bestv; bestloc = g0 ? (uint)(2 * p) : bestloc;
      bool g1 = n1 > bestv; bestv = g1 ? n1 : bestv; bestloc = g1 ? (uint)(2 * p + 1) : bestloc;
    }
    // wave64 value-max (6 dpp+max, lands full in lane 63)
    float m = bestv;
    m = dpp_fmax_step<0x111, 0xf>(m);   // row_shr:1
    m = dpp_fmax_step<0x112, 0xf>(m);   // row_shr:2
    m = dpp_fmax_step<0x114, 0xf>(m);   // row_shr:4
    m = dpp_fmax_step<0x118, 0xf>(m);   // row_shr:8
    m = dpp_fmax_step<0x142, 0xa>(m);   // row_bcast:15 -> rows 1,3
    m = dpp_fmax_step<0x143, 0xc>(m);   // row_bcast:31 -> rows 2,3
    float wmax = __uint_as_float((uint)__builtin_amdgcn_readlane((int)__float_as_uint(m), 63));
    ull mask = __ballot(bestv == wmax);
    int wl = __ffsll((long long)mask) - 1;            // first lane = smallest j
    uint loc = (uint)__builtin_amdgcn_readlane((int)bestloc, wl);
    uint jg = (uint)(((wid << 6) + wl) * 8) + loc;    // wave-winner global index
    int pb = s & 1;
    if (lane == 0) skey[pb][wid] = ((ull)__float_as_uint(wmax) << 32) | (ull)(~jg);
    __syncthreads();                                  // lgkm-only barrier
    ull k0 = skey[pb][0], k1 = skey[pb][1], k2 = skey[pb][2], k3 = skey[pb][3];
    uint w0 = ~(uint)k0, w1 = ~(uint)k1, w2 = ~(uint)k2, w3 = ~(uint)k3;
    float x0 = sptx[w0], y0 = spty[w0], z0 = sptz[w0];   // 12 speculative broadcast
    float x1 = sptx[w1], y1 = spty[w1], z1 = sptz[w1];   // reads, overlap the tree
    float x2 = sptx[w2], y2 = spty[w2], z2 = sptz[w2];
    float x3 = sptx[w3], y3 = spty[w3], z3 = sptz[w3];
    bool t01 = k0 > k1, t23 = k2 > k3;
    ull ka = t01 ? k0 : k1;  float xa = t01 ? x0 : x1, ya = t01 ? y0 : y1, za = t01 ? z0 : z1;
    ull kb = t23 ? k2 : k3;  float xb = t23 ? x2 : x3, yb = t23 ? y2 : y3, zb = t23 ? z2 : z3;
    bool tw = ka > kb;
    far = ~(uint)(tw ? ka : kb);
    cx = tw ? xa : xb; cy = tw ? ya : yb; cz = tw ? za : zb;
  }
  __syncthreads();
  for (int s2 = tid; s2 < S_; s2 += 256) {
    int f = sfar[s2];
    fidx[b * S_ + s2] = f;
    int o = (b * S_ + s2) * 3;
    out_xyz[o] = sptx[f]; out_xyz[o + 1] = spty[f]; out_xyz[o + 2] = sptz[f];
  }
}

// ---------------- txp: x[b][c][n] fp32 -> xT[b][n][c] bf16 (LDS-tiled) ----------
__global__ __launch_bounds__(256) void txp_kernel(const float* __restrict__ x,
                                                  ushort_t* __restrict__ xT) {
  __shared__ float tile[64][65];
  int b = blockIdx.x >> 5;            // 16 b x 32 n-tiles
  int n0 = (blockIdx.x & 31) * 64;
  int nn = threadIdx.x & 63, c4 = threadIdx.x >> 6;
  const float* xb = x + (size_t)b * (DIN * N_);
#pragma unroll
  for (int i = 0; i < 16; ++i) {
    int c = c4 * 16 + i;
    tile[nn][c] = xb[(size_t)c * N_ + n0 + nn];   // coalesced along n
  }
  __syncthreads();
#pragma unroll
  for (int i = 0; i < 16; ++i) {
    int n = c4 * 16 + i;
    xT[((size_t)b * N_ + n0 + n) * 64 + nn] = (ushort_t)bf16b(tile[n][nn]);  // coalesced along c
  }
}

// ---------------- prep: B-fragment packs for both GEMMs ----------------
__global__ __launch_bounds__(256) void prep_kernel(const float* __restrict__ W1,
                                                   const float* __restrict__ W2,
                                                   ushort_t* __restrict__ Bp1,
                                                   ushort_t* __restrict__ Bpd,
                                                   ushort_t* __restrict__ Bp2) {
  int i = blockIdx.x * 256 + threadIdx.x;   // 16384
  int j2 = i & 7, l = (i >> 3) & 63;
  {
    int kc = (i >> 9) & 3, nt = i >> 11;
    int o2 = nt * 16 + (l & 15);
    int c2 = kc * 32 + ((l >> 4) * 8) + j2;
    Bp2[i] = (ushort_t)bf16b(W2[o2 * 128 + c2]);
  }
  if (i < 8192) {
    int kc = (i >> 9) & 1, nt = (i >> 10) & 7;
    int o2 = nt * 16 + (l & 15);
    int c2 = kc * 32 + ((l >> 4) * 8) + j2;
    float wa = W1[o2 * 128 + c2];
    float wb = W1[o2 * 128 + 64 + c2];
    Bp1[i] = (ushort_t)bf16b(wa);
    Bpd[i] = (ushort_t)bf16b(wb - wa);
  }
}

// ---------------- GEMM1 (MFMA bf16) + inline ball query, direct-frag gather -------
// A-fragments loaded straight from xT (row gik = contiguous 64 bf16); no LDS staging,
// no barrier. h1T[g][k][o] = W1a@xg + (W1b-W1a)@ctr, CT layout D[m=k][n=o].
__global__ __launch_bounds__(256) void gemm1_kernel(const ushort_t* __restrict__ xT,
    const float* __restrict__ coords, const int* __restrict__ fidx,
    const ushort_t* __restrict__ Bp1, const ushort_t* __restrict__ Bpd,
    ushort_t* __restrict__ h1T, float* __restrict__ psum, float* __restrict__ psq) {
  __shared__ int sgidx[4][K_];
  int tid = threadIdx.x;
  int lane = tid & 63, wid = tid >> 6;
  int g = __builtin_amdgcn_readfirstlane(blockIdx.x * 4 + wid);
  int b = g >> 9;
  const float* cb = coords + (size_t)b * (N_ * 3);
  int nf = fidx[g];
  // ---- inline ball query (exact fp32, first-32 within radius, pad with first) ----
  {
    float cx = cb[3 * nf], cy = cb[3 * nf + 1], cz = cb[3 * nf + 2];
    int cnt = 0, first = 0;
    bool hasfirst = false;
    for (int base = 0; base < N_; base += 64) {
      int j = base + lane;
      float dx = __fsub_rn(cb[3 * j], cx);
      float dy = __fsub_rn(cb[3 * j + 1], cy);
      float dz = __fsub_rn(cb[3 * j + 2], cz);
      float d = __fadd_rn(__fadd_rn(__fmul_rn(dx, dx), __fmul_rn(dy, dy)), __fmul_rn(dz, dz));
      bool in = (d <= 0.25f);
      ull m = __ballot(in);
      if (in) {
        int pos = cnt + __popcll(m & ((1ull << lane) - 1ull));
        if (pos < K_) sgidx[wid][pos] = j;
      }
      if (!hasfirst && m) { first = base + (__ffsll((long long)m) - 1); hasfirst = true; }
      cnt += __popcll(m);
      if (cnt >= K_) break;
    }
    if (cnt < K_) {
      for (int p = cnt + lane; p < K_; p += 64) sgidx[wid][p] = first;
    }
  }
  int l15 = lane & 15, r8 = (lane >> 4) * 8;
  const ushort_t* xb64 = xT + (size_t)b * N_ * 64;
  f32x4 acc[2][8];
#pragma unroll
  for (int nt = 0; nt < 8; ++nt) acc[0][nt] = (f32x4){0.f, 0.f, 0.f, 0.f};
  // center term: A-frag = broadcast centroid features (uniform row nf)
#pragma unroll
  for (int kc = 0; kc < 2; ++kc) {
    bf16x8 cu = *(const bf16x8*)(xb64 + nf * 64 + kc * 32 + r8);
#pragma unroll
    for (int nt = 0; nt < 8; ++nt) {
      bf16x8 bf = *(const bf16x8*)(Bpd + ((nt * 2 + kc) * 64 + lane) * 8);
      acc[0][nt] = __builtin_amdgcn_mfma_f32_16x16x32_bf16(cu, bf, acc[0][nt], 0, 0, 0);
    }
  }
#pragma unroll
  for (int nt = 0; nt < 8; ++nt) acc[1][nt] = acc[0][nt];
  // grouped term: direct A-fragment loads, row = sgidx[k], cols kc*32+r8..+7
  int gi0 = sgidx[wid][l15];
  int gi1 = sgidx[wid][16 + l15];
#pragma unroll
  for (int kc = 0; kc < 2; ++kc) {
    bf16x8 af0 = *(const bf16x8*)(xb64 + (size_t)gi0 * 64 + kc * 32 + r8);
    bf16x8 af1 = *(const bf16x8*)(xb64 + (size_t)gi1 * 64 + kc * 32 + r8);
#pragma unroll
    for (int nt = 0; nt < 8; ++nt) {
      bf16x8 bf = *(const bf16x8*)(Bp1 + ((nt * 2 + kc) * 64 + lane) * 8);
      acc[0][nt] = __builtin_amdgcn_mfma_f32_16x16x32_bf16(af0, bf, acc[0][nt], 0, 0, 0);
      acc[1][nt] = __builtin_amdgcn_mfma_f32_16x16x32_bf16(af1, bf, acc[1][nt], 0, 0, 0);
    }
  }
  // stats per o (lane's 8 acc vals share o = nt*16+l15)
#pragma unroll
  for (int nt = 0; nt < 8; ++nt) {
    float s = 0.f, q = 0.f;
#pragma unroll
    for (int mt = 0; mt < 2; ++mt)
#pragma unroll
      for (int r = 0; r < 4; ++r) { float a = acc[mt][nt][r]; s += a; q = fmaf(a, a, q); }
    s += __shfl_xor(s, 16, 64); s += __shfl_xor(s, 32, 64);
    q += __shfl_xor(q, 16, 64); q += __shfl_xor(q, 32, 64);
    if (lane < 16) {
      int o = nt * 16 + lane;
      psum[o * G_ + g] = s; psq[o * G_ + g] = q;
    }
  }
  // transposed store h1T[g][k][o], k = mt*16+(lane>>4)*4+r, o = nt*16+l15
#pragma unroll
  for (int mt = 0; mt < 2; ++mt)
#pragma unroll
    for (int r = 0; r < 4; ++r) {
      int k = mt * 16 + (lane >> 4) * 4 + r;
      ushort_t* dst = h1T + (size_t)g * 4096 + k * 128 + l15;
#pragma unroll
      for (int nt = 0; nt < 8; ++nt)
        dst[nt * 16] = (ushort_t)bf16b(acc[mt][nt][r]);
    }
}

// ---------------- BN finalize: per-channel mean/var -> scale/shift ----------------
__global__ __launch_bounds__(256) void bn_finalize(const float* __restrict__ psum,
    const float* __restrict__ psq, const float* __restrict__ gamma,
    const float* __restrict__ beta, float* __restrict__ bnp) {
  int o = blockIdx.x, tid = threadIdx.x;
  double s = 0.0, q = 0.0;
  for (int g = tid; g < G_; g += 256) { s += (double)psum[o * G_ + g]; q += (double)psq[o * G_ + g]; }
  __shared__ double ss[256], qq[256];
  ss[tid] = s; qq[tid] = q; __syncthreads();
  for (int off = 128; off > 0; off >>= 1) {
    if (tid < off) { ss[tid] += ss[tid + off]; qq[tid] += qq[tid + off]; }
    __syncthreads();
  }
  if (tid == 0) {
    double n = 262144.0;
    double mean = ss[0] / n, var = qq[0] / n - mean * mean;
    float scv = (float)((double)gamma[o] / sqrt(var + 1e-5));
    bnp[2 * o] = scv;
    bnp[2 * o + 1] = (float)((double)beta[o] - mean * (double)scv);
  }
}

// ---------------- GEMM2 (MFMA bf16): CT layout D[k][o], per-(g,o) stats ----------
__global__ __launch_bounds__(256) void gemm2_kernel(const ushort_t* __restrict__ h1T,
    const ushort_t* __restrict__ Bp2, const float* __restrict__ bnp1,
    float* __restrict__ psum, float* __restrict__ psq,
    float* __restrict__ hmax, float* __restrict__ hmin) {
  __shared__ ushort_t actT[4][32 * ATS];
  int tid = threadIdx.x;
  int lane = tid & 63, wid = tid >> 6;
  int g = __builtin_amdgcn_readfirstlane(blockIdx.x * 4 + wid);
  ushort_t* aw = actT[wid];
  int c0 = (lane & 15) * 8;
  float s1[8], t1[8];
#pragma unroll
  for (int jj = 0; jj < 8; ++jj) { s1[jj] = bnp1[2 * (c0 + jj)]; t1[jj] = bnp1[2 * (c0 + jj) + 1]; }
  const uint4* src = (const uint4*)(h1T + (size_t)g * 4096);
#pragma unroll
  for (int t = 0; t < 8; ++t) {
    int idx = t * 64 + lane;
    uint4 v = src[idx];
    int k = idx >> 4;
    uint w[4] = {v.x, v.y, v.z, v.w};
    uint o4[4];
#pragma unroll
    for (int p2 = 0; p2 < 4; ++p2) {
      float a0 = fmaxf(fmaf(bf2f(w[p2] & 0xffffu), s1[2 * p2], t1[2 * p2]), 0.f);
      float a1 = fmaxf(fmaf(bf2f(w[p2] >> 16), s1[2 * p2 + 1], t1[2 * p2 + 1]), 0.f);
      o4[p2] = (bf16b(a1) << 16) | bf16b(a0);
    }
    *(uint4*)(aw + k * ATS + c0) = make_uint4(o4[0], o4[1], o4[2], o4[3]);
  }
  __syncthreads();
  f32x4 acc[2][8];
#pragma unroll
  for (int mt = 0; mt < 2; ++mt)
#pragma unroll
    for (int nt = 0; nt < 8; ++nt) acc[mt][nt] = (f32x4){0.f, 0.f, 0.f, 0.f};
#pragma unroll
  for (int kc = 0; kc < 4; ++kc) {
    bf16x8 afrag[2];
#pragma unroll
    for (int mt = 0; mt < 2; ++mt)
      afrag[mt] = *(const bf16x8*)(aw + (mt * 16 + (lane & 15)) * ATS + kc * 32 + (lane >> 4) * 8);
#pragma unroll
    for (int nt = 0; nt < 8; ++nt) {
      bf16x8 bfrag = *(const bf16x8*)(Bp2 + ((nt * 4 + kc) * 64 + lane) * 8);
      acc[0][nt] = __builtin_amdgcn_mfma_f32_16x16x32_bf16(afrag[0], bfrag, acc[0][nt], 0, 0, 0);
      acc[1][nt] = __builtin_amdgcn_mfma_f32_16x16x32_bf16(afrag[1], bfrag, acc[1][nt], 0, 0, 0);
    }
  }
#pragma unroll
  for (int nt = 0; nt < 8; ++nt) {
    float s = 0.f, q = 0.f, mx = -1e30f, mn = 1e30f;
#pragma unroll
    for (int mt = 0; mt < 2; ++mt)
#pragma unroll
      for (int r = 0; r < 4; ++r) {
        float a = acc[mt][nt][r];
        s += a; q = fmaf(a, a, q); mx = fmaxf(mx, a); mn = fminf(mn, a);
      }
    s += __shfl_xor(s, 16, 64); s += __shfl_xor(s, 32, 64);
    q += __shfl_xor(q, 16, 64); q += __shfl_xor(q, 32, 64);
    mx = fmaxf(mx, __shfl_xor(mx, 16, 64)); mx = fmaxf(mx, __shfl_xor(mx, 32, 64));
    mn = fminf(mn, __shfl_xor(mn, 16, 64)); mn = fminf(mn, __shfl_xor(mn, 32, 64));
    if (lane < 16) {
      int o = nt * 16 + lane;
      psum[o * G_ + g] = s; psq[o * G_ + g] = q;
      hmax[o * G_ + g] = mx; hmin[o * G_ + g] = mn;
    }
  }
}

// ---------------- pool: out[b,o,s] = relu(s2 * (s2>=0 ? max : min) + t2) ----------------
__global__ __launch_bounds__(256) void pool_kernel(const float* __restrict__ hmax,
    const float* __restrict__ hmin, const float* __restrict__ bnp2,
    float* __restrict__ out) {
  int i = blockIdx.x * 256 + threadIdx.x;   // 1,048,576 = (b*128+o)*512+s
  int s = i & 511;
  int o = (i >> 9) & 127;
  int b = i >> 16;
  int g = b * 512 + s;
  float scv = bnp2[2 * o], tf = bnp2[2 * o + 1];
  float v = (scv >= 0.f) ? hmax[o * G_ + g] : hmin[o * G_ + g];
  out[i] = fmaxf(fmaf(scv, v, tf), 0.f);
}

extern "C" void kernel_launch(void* const* d_in, const int* in_sizes, int n_in,
                              void* d_out, int out_size, void* d_ws, size_t ws_size,
                              hipStream_t stream) {
  const float* x      = (const float*)d_in[0];
  const float* coords = (const float*)d_in[1];
  const float* W1     = (const float*)d_in[2];
  const float* W2     = (const float*)d_in[3];
  const float* gamma1 = (const float*)d_in[4];
  const float* beta1  = (const float*)d_in[5];
  const float* gamma2 = (const float*)d_in[6];
  const float* beta2  = (const float*)d_in[7];
  float* out = (float*)d_out;
  char* ws = (char*)d_ws;
  ushort_t* h1T  = (ushort_t*)(ws);               // 67,108,864 B  (h1T[g][k][o] bf16)
  float* psum1 = (float*)(ws + 67108864);         // 4 MB each below
  float* psq1  = (float*)(ws + 71303168);
  float* psum2 = (float*)(ws + 75497472);         // NOTE: first 4 MB aliased by xT
  float* psq2  = (float*)(ws + 79691776);         //   (xT dead before gemm2 writes)
  ushort_t* xT = (ushort_t*)(ws + 75497472);      // 4 MB  xT[b][n][c] bf16
  float* hmax  = (float*)(ws + 83886080);
  float* hmin  = (float*)(ws + 88080384);
  ushort_t* Bp1 = (ushort_t*)(ws + 92274688);     // 16 KB
  ushort_t* Bpd = (ushort_t*)(ws + 92291072);     // 16 KB
  ushort_t* Bp2 = (ushort_t*)(ws + 92307456);     // 32 KB
  float* bnp1  = (float*)(ws + 92340224);
  float* bnp2  = (float*)(ws + 92341248);
  int* fidx    = (int*)(ws + 92342272);           // 32 KB, end 92,375,040 B

  txp_kernel<<<512, 256, 0, stream>>>(x, xT);
  prep_kernel<<<64, 256, 0, stream>>>(W1, W2, Bp1, Bpd, Bp2);
  fps_kernel<<<16, 256, 0, stream>>>(coords, fidx, out);
  gemm1_kernel<<<2048, 256, 0, stream>>>(xT, coords, fidx, Bp1, Bpd, h1T, psum1, psq1);
  bn_finalize<<<128, 256, 0, stream>>>(psum1, psq1, gamma1, beta1, bnp1);
  gemm2_kernel<<<2048, 256, 0, stream>>>(h1T, Bp2, bnp1, psum2, psq2, hmax, hmin);
  bn_finalize<<<128, 256, 0, stream>>>(psum2, psq2, gamma2, beta2, bnp2);
  pool_kernel<<<4096, 256, 0, stream>>>(hmax, hmin, bnp2, out + 24576);
}

// Round 11
// 347.225 us; speedup vs baseline: 1.3338x; 1.0221x over previous
//
#include <hip/hip_runtime.h>
#include <cstdint>

typedef unsigned int uint;
typedef unsigned short ushort_t;
typedef unsigned long long ull;
typedef __attribute__((ext_vector_type(8))) short bf16x8;
typedef __attribute__((ext_vector_type(4))) float f32x4;
typedef __attribute__((ext_vector_type(2))) float f32x2;

#define B_   16
#define N_   2048
#define S_   512
#define G_   8192       // B_*S_
#define DIN  64
#define DOUT 128
#define K_   32
#define ATS  136        // gemm2 actT row stride (bf16)

__device__ __forceinline__ uint bf16b(float f) {
  uint u = __float_as_uint(f);
  return (u + 0x7fffu + ((u >> 16) & 1u)) >> 16;
}
__device__ __forceinline__ float bf2f(uint b) { return __uint_as_float(b << 16); }

template<int CTRL, int RM>
__device__ __forceinline__ float dpp_fmax_step(float x) {
  float y = __uint_as_float((uint)__builtin_amdgcn_update_dpp(
      (int)__float_as_uint(x), (int)__float_as_uint(x), CTRL, RM, 0xf, true));
  return fmaxf(x, y);   // bound_ctrl zero-fill: dists >= 0 -> identity for max
}

// ---------------- front: fps (blocks 0-15) | txp (16-527) | prep (528-591) --------
// fps is the R8-proven 228us structure (FROZEN). txp/prep run on idle CUs during fps.
__global__ __launch_bounds__(256) void front_kernel(const float* __restrict__ coords,
    const float* __restrict__ x, const float* __restrict__ W1,
    const float* __restrict__ W2, int* __restrict__ fidx,
    float* __restrict__ out_xyz, ushort_t* __restrict__ xT,
    ushort_t* __restrict__ Bp1, ushort_t* __restrict__ Bpd,
    ushort_t* __restrict__ Bp2) {
  int blk = blockIdx.x;
  int tid = threadIdx.x;
  if (blk < 16) {
    // ------------------ FPS: 4 waves x 8 pts/lane, exact fp32 ------------------
    int b = blk;
    const float* cb = coords + (size_t)b * (N_ * 3);
    __shared__ float sptx[N_], spty[N_], sptz[N_];
    __shared__ ull   skey[2][4];
    __shared__ int   sfar[S_];
    int lane = tid & 63, wid = tid >> 6;
    for (int j = tid; j < N_; j += 256) {
      sptx[j] = cb[3 * j]; spty[j] = cb[3 * j + 1]; sptz[j] = cb[3 * j + 2];
    }
    f32x2 px[4], py[4], pz[4], dist[4];
    int j0 = tid * 8;
#pragma unroll
    for (int p = 0; p < 4; ++p) {
      int j = j0 + 2 * p;
      px[p].x = cb[3 * j];     py[p].x = cb[3 * j + 1]; pz[p].x = cb[3 * j + 2];
      px[p].y = cb[3 * j + 3]; py[p].y = cb[3 * j + 4]; pz[p].y = cb[3 * j + 5];
      dist[p].x = 1e10f; dist[p].y = 1e10f;
    }
    float cx = cb[0], cy = cb[1], cz = cb[2];
    uint far = 0;
    __syncthreads();
    for (int s = 0; s < S_; ++s) {
      if (tid == 0) sfar[s] = (int)far;          // PRE-update far (matches jax scan)
      f32x2 c2x = {cx, cx}, c2y = {cy, cy}, c2z = {cz, cz};
      float bestv = -1.f; uint bestloc = 0;
#pragma unroll
      for (int p = 0; p < 4; ++p) {
        f32x2 dx, dy, dz, qx, qy, qz, s1, s2;
        asm("v_pk_add_f32 %0, %1, %2 neg_lo:[0,1] neg_hi:[0,1]" : "=v"(dx) : "v"(px[p]), "v"(c2x));
        asm("v_pk_add_f32 %0, %1, %2 neg_lo:[0,1] neg_hi:[0,1]" : "=v"(dy) : "v"(py[p]), "v"(c2y));
        asm("v_pk_add_f32 %0, %1, %2 neg_lo:[0,1] neg_hi:[0,1]" : "=v"(dz) : "v"(pz[p]), "v"(c2z));
        asm("v_pk_mul_f32 %0, %1, %1" : "=v"(qx) : "v"(dx));
        asm("v_pk_mul_f32 %0, %1, %1" : "=v"(qy) : "v"(dy));
        asm("v_pk_mul_f32 %0, %1, %1" : "=v"(qz) : "v"(dz));
        asm("v_pk_add_f32 %0, %1, %2" : "=v"(s1) : "v"(qx), "v"(qy));
        asm("v_pk_add_f32 %0, %1, %2" : "=v"(s2) : "v"(s1), "v"(qz));
        float n0 = fminf(dist[p].x, s2.x);
        float n1 = fminf(dist[p].y, s2.y);
        dist[p].x = n0; dist[p].y = n1;
        bool g0 = n0 > bestv; bestv = g0 ? n0 : bestv; bestloc = g0 ? (uint)(2 * p) : bestloc;
        bool g1 = n1 > bestv; bestv = g1 ? n1 : bestv; bestloc = g1 ? (uint)(2 * p + 1) : bestloc;
      }
      float m = bestv;
      m = dpp_fmax_step<0x111, 0xf>(m);   // row_shr:1
      m = dpp_fmax_step<0x112, 0xf>(m);   // row_shr:2
      m = dpp_fmax_step<0x114, 0xf>(m);   // row_shr:4
      m = dpp_fmax_step<0x118, 0xf>(m);   // row_shr:8
      m = dpp_fmax_step<0x142, 0xa>(m);   // row_bcast:15 -> rows 1,3
      m = dpp_fmax_step<0x143, 0xc>(m);   // row_bcast:31 -> rows 2,3
      float wmax = __uint_as_float((uint)__builtin_amdgcn_readlane((int)__float_as_uint(m), 63));
      ull mask = __ballot(bestv == wmax);
      int wl = __ffsll((long long)mask) - 1;            // first lane = smallest j
      uint loc = (uint)__builtin_amdgcn_readlane((int)bestloc, wl);
      uint jg = (uint)(((wid << 6) + wl) * 8) + loc;    // wave-winner global index
      int pb = s & 1;
      if (lane == 0) skey[pb][wid] = ((ull)__float_as_uint(wmax) << 32) | (ull)(~jg);
      __syncthreads();                                  // lgkm-only barrier
      ull k0 = skey[pb][0], k1 = skey[pb][1], k2 = skey[pb][2], k3 = skey[pb][3];
      uint w0 = ~(uint)k0, w1 = ~(uint)k1, w2 = ~(uint)k2, w3 = ~(uint)k3;
      float x0 = sptx[w0], y0 = spty[w0], z0 = sptz[w0];   // 12 speculative broadcast
      float x1 = sptx[w1], y1 = spty[w1], z1 = sptz[w1];   // reads, overlap the tree
      float x2 = sptx[w2], y2 = spty[w2], z2 = sptz[w2];
      float x3 = sptx[w3], y3 = spty[w3], z3 = sptz[w3];
      bool t01 = k0 > k1, t23 = k2 > k3;
      ull ka = t01 ? k0 : k1;  float xa = t01 ? x0 : x1, ya = t01 ? y0 : y1, za = t01 ? z0 : z1;
      ull kb = t23 ? k2 : k3;  float xb = t23 ? x2 : x3, yb = t23 ? y2 : y3, zb = t23 ? z2 : z3;
      bool tw = ka > kb;
      far = ~(uint)(tw ? ka : kb);
      cx = tw ? xa : xb; cy = tw ? ya : yb; cz = tw ? za : zb;
    }
    __syncthreads();
    for (int s2 = tid; s2 < S_; s2 += 256) {
      int f = sfar[s2];
      fidx[b * S_ + s2] = f;
      int o = (b * S_ + s2) * 3;
      out_xyz[o] = sptx[f]; out_xyz[o + 1] = spty[f]; out_xyz[o + 2] = sptz[f];
    }
  } else if (blk < 528) {
    // ------------------ txp: x[b][c][n] fp32 -> xT[b][n][c] bf16 ------------------
    __shared__ float tile[64][65];
    int blk2 = blk - 16;
    int b = blk2 >> 5;            // 16 b x 32 n-tiles
    int n0 = (blk2 & 31) * 64;
    int nn = tid & 63, c4 = tid >> 6;
    const float* xb = x + (size_t)b * (DIN * N_);
#pragma unroll
    for (int i = 0; i < 16; ++i) {
      int c = c4 * 16 + i;
      tile[nn][c] = xb[(size_t)c * N_ + n0 + nn];   // coalesced along n
    }
    __syncthreads();
#pragma unroll
    for (int i = 0; i < 16; ++i) {
      int n = c4 * 16 + i;
      xT[((size_t)b * N_ + n0 + n) * 64 + nn] = (ushort_t)bf16b(tile[n][nn]);  // coalesced along c
    }
  } else {
    // ------------------ prep: B-fragment packs for both GEMMs ------------------
    int i = (blk - 528) * 256 + tid;   // 16384
    int j2 = i & 7, l = (i >> 3) & 63;
    {
      int kc = (i >> 9) & 3, nt = i >> 11;
      int o2 = nt * 16 + (l & 15);
      int c2 = kc * 32 + ((l >> 4) * 8) + j2;
      Bp2[i] = (ushort_t)bf16b(W2[o2 * 128 + c2]);
    }
    if (i < 8192) {
      int kc = (i >> 9) & 1, nt = (i >> 10) & 7;
      int o2 = nt * 16 + (l & 15);
      int c2 = kc * 32 + ((l >> 4) * 8) + j2;
      float wa = W1[o2 * 128 + c2];
      float wb = W1[o2 * 128 + 64 + c2];
      Bp1[i] = (ushort_t)bf16b(wa);
      Bpd[i] = (ushort_t)bf16b(wb - wa);
    }
  }
}

// ---------------- GEMM1 (MFMA bf16) + inline ball query: stats only --------------
// h1 computed (CT layout D[m=k][n=o]) for psum/psq; NOT stored. gidx -> global.
__global__ __launch_bounds__(256) void gemm1_kernel(const ushort_t* __restrict__ xT,
    const float* __restrict__ coords, const int* __restrict__ fidx,
    const ushort_t* __restrict__ Bp1, const ushort_t* __restrict__ Bpd,
    int* __restrict__ gidx, float* __restrict__ psum, float* __restrict__ psq) {
  __shared__ int sgidx[4][K_];
  int tid = threadIdx.x;
  int lane = tid & 63, wid = tid >> 6;
  int g = __builtin_amdgcn_readfirstlane(blockIdx.x * 4 + wid);
  int b = g >> 9;
  const float* cb = coords + (size_t)b * (N_ * 3);
  int nf = fidx[g];
  // ---- inline ball query (exact fp32, first-32 within radius, pad with first) ----
  {
    float cx = cb[3 * nf], cy = cb[3 * nf + 1], cz = cb[3 * nf + 2];
    int cnt = 0, first = 0;
    bool hasfirst = false;
    for (int base = 0; base < N_; base += 64) {
      int j = base + lane;
      float dx = __fsub_rn(cb[3 * j], cx);
      float dy = __fsub_rn(cb[3 * j + 1], cy);
      float dz = __fsub_rn(cb[3 * j + 2], cz);
      float d = __fadd_rn(__fadd_rn(__fmul_rn(dx, dx), __fmul_rn(dy, dy)), __fmul_rn(dz, dz));
      bool in = (d <= 0.25f);
      ull m = __ballot(in);
      if (in) {
        int pos = cnt + __popcll(m & ((1ull << lane) - 1ull));
        if (pos < K_) sgidx[wid][pos] = j;
      }
      if (!hasfirst && m) { first = base + (__ffsll((long long)m) - 1); hasfirst = true; }
      cnt += __popcll(m);
      if (cnt >= K_) break;
    }
    if (cnt < K_) {
      for (int p = cnt + lane; p < K_; p += 64) sgidx[wid][p] = first;
    }
  }
  if (lane < K_) gidx[g * K_ + lane] = sgidx[wid][lane];
  int l15 = lane & 15, r8 = (lane >> 4) * 8;
  const ushort_t* xb64 = xT + (size_t)b * N_ * 64;
  f32x4 acc[2][8];
#pragma unroll
  for (int nt = 0; nt < 8; ++nt) acc[0][nt] = (f32x4){0.f, 0.f, 0.f, 0.f};
#pragma unroll
  for (int kc = 0; kc < 2; ++kc) {
    bf16x8 cu = *(const bf16x8*)(xb64 + nf * 64 + kc * 32 + r8);
#pragma unroll
    for (int nt = 0; nt < 8; ++nt) {
      bf16x8 bf = *(const bf16x8*)(Bpd + ((nt * 2 + kc) * 64 + lane) * 8);
      acc[0][nt] = __builtin_amdgcn_mfma_f32_16x16x32_bf16(cu, bf, acc[0][nt], 0, 0, 0);
    }
  }
#pragma unroll
  for (int nt = 0; nt < 8; ++nt) acc[1][nt] = acc[0][nt];
  int gi0 = sgidx[wid][l15];
  int gi1 = sgidx[wid][16 + l15];
#pragma unroll
  for (int kc = 0; kc < 2; ++kc) {
    bf16x8 af0 = *(const bf16x8*)(xb64 + (size_t)gi0 * 64 + kc * 32 + r8);
    bf16x8 af1 = *(const bf16x8*)(xb64 + (size_t)gi1 * 64 + kc * 32 + r8);
#pragma unroll
    for (int nt = 0; nt < 8; ++nt) {
      bf16x8 bf = *(const bf16x8*)(Bp1 + ((nt * 2 + kc) * 64 + lane) * 8);
      acc[0][nt] = __builtin_amdgcn_mfma_f32_16x16x32_bf16(af0, bf, acc[0][nt], 0, 0, 0);
      acc[1][nt] = __builtin_amdgcn_mfma_f32_16x16x32_bf16(af1, bf, acc[1][nt], 0, 0, 0);
    }
  }
#pragma unroll
  for (int nt = 0; nt < 8; ++nt) {
    float s = 0.f, q = 0.f;
#pragma unroll
    for (int mt = 0; mt < 2; ++mt)
#pragma unroll
      for (int r = 0; r < 4; ++r) { float a = acc[mt][nt][r]; s += a; q = fmaf(a, a, q); }
    s += __shfl_xor(s, 16, 64); s += __shfl_xor(s, 32, 64);
    q += __shfl_xor(q, 16, 64); q += __shfl_xor(q, 32, 64);
    if (lane < 16) {
      int o = nt * 16 + lane;
      psum[o * G_ + g] = s; psq[o * G_ + g] = q;
    }
  }
}

// ---------------- BN finalize: per-channel mean/var -> scale/shift ----------------
__global__ __launch_bounds__(256) void bn_finalize(const float* __restrict__ psum,
    const float* __restrict__ psq, const float* __restrict__ gamma,
    const float* __restrict__ beta, float* __restrict__ bnp) {
  int o = blockIdx.x, tid = threadIdx.x;
  double s = 0.0, q = 0.0;
  for (int g = tid; g < G_; g += 256) { s += (double)psum[o * G_ + g]; q += (double)psq[o * G_ + g]; }
  __shared__ double ss[256], qq[256];
  ss[tid] = s; qq[tid] = q; __syncthreads();
  for (int off = 128; off > 0; off >>= 1) {
    if (tid < off) { ss[tid] += ss[tid + off]; qq[tid] += qq[tid + off]; }
    __syncthreads();
  }
  if (tid == 0) {
    double n = 262144.0;
    double mean = ss[0] / n, var = qq[0] / n - mean * mean;
    float scv = (float)((double)gamma[o] / sqrt(var + 1e-5));
    bnp[2 * o] = scv;
    bnp[2 * o + 1] = (float)((double)beta[o] - mean * (double)scv);
  }
}

// ---------------- GEMM2 (MFMA bf16): RECOMPUTE h1 from xT, then W2 @ relu(bn1) ----
// Phase 1: h1 = W1a@xg + Wd@ctr (identical MFMA to gemm1, CT layout).
// Phase 2: bn1+relu in-register -> bf16 -> per-wave LDS actT[k][c] -> 64 MFMA.
__global__ __launch_bounds__(256) void gemm2_kernel(const ushort_t* __restrict__ xT,
    const int* __restrict__ fidx, const int* __restrict__ gidx,
    const ushort_t* __restrict__ Bp1, const ushort_t* __restrict__ Bpd,
    const ushort_t* __restrict__ Bp2, const float* __restrict__ bnp1,
    float* __restrict__ psum, float* __restrict__ psq,
    float* __restrict__ hmax, float* __restrict__ hmin) {
  __shared__ ushort_t actT[4][32 * ATS];
  int tid = threadIdx.x;
  int lane = tid & 63, wid = tid >> 6;
  int g = __builtin_amdgcn_readfirstlane(blockIdx.x * 4 + wid);
  int b = g >> 9;
  int l15 = lane & 15, r8 = (lane >> 4) * 8;
  const ushort_t* xb64 = xT + (size_t)b * N_ * 64;
  int nf = fidx[g];
  // ---- phase 1: recompute h1 (CT layout: k = mt*16+(lane>>4)*4+r, o = nt*16+l15) --
  f32x4 acc[2][8];
#pragma unroll
  for (int nt = 0; nt < 8; ++nt) acc[0][nt] = (f32x4){0.f, 0.f, 0.f, 0.f};
#pragma unroll
  for (int kc = 0; kc < 2; ++kc) {
    bf16x8 cu = *(const bf16x8*)(xb64 + nf * 64 + kc * 32 + r8);
#pragma unroll
    for (int nt = 0; nt < 8; ++nt) {
      bf16x8 bf = *(const bf16x8*)(Bpd + ((nt * 2 + kc) * 64 + lane) * 8);
      acc[0][nt] = __builtin_amdgcn_mfma_f32_16x16x32_bf16(cu, bf, acc[0][nt], 0, 0, 0);
    }
  }
#pragma unroll
  for (int nt = 0; nt < 8; ++nt) acc[1][nt] = acc[0][nt];
  int gi0 = gidx[g * K_ + l15];
  int gi1 = gidx[g * K_ + 16 + l15];
#pragma unroll
  for (int kc = 0; kc < 2; ++kc) {
    bf16x8 af0 = *(const bf16x8*)(xb64 + (size_t)gi0 * 64 + kc * 32 + r8);
    bf16x8 af1 = *(const bf16x8*)(xb64 + (size_t)gi1 * 64 + kc * 32 + r8);
#pragma unroll
    for (int nt = 0; nt < 8; ++nt) {
      bf16x8 bf = *(const bf16x8*)(Bp1 + ((nt * 2 + kc) * 64 + lane) * 8);
      acc[0][nt] = __builtin_amdgcn_mfma_f32_16x16x32_bf16(af0, bf, acc[0][nt], 0, 0, 0);
      acc[1][nt] = __builtin_amdgcn_mfma_f32_16x16x32_bf16(af1, bf, acc[1][nt], 0, 0, 0);
    }
  }
  // ---- phase 2: bn1 + relu -> bf16 -> actT[k][o] (per-wave; same-wave LDS dep) ----
  float s1v[8], t1v[8];
#pragma unroll
  for (int nt = 0; nt < 8; ++nt) {
    int o = nt * 16 + l15;
    s1v[nt] = bnp1[2 * o]; t1v[nt] = bnp1[2 * o + 1];
  }
  ushort_t* aw = actT[wid];
#pragma unroll
  for (int mt = 0; mt < 2; ++mt)
#pragma unroll
    for (int r = 0; r < 4; ++r) {
      int k = mt * 16 + (lane >> 4) * 4 + r;
#pragma unroll
      for (int nt = 0; nt < 8; ++nt) {
        float a = fmaxf(fmaf(acc[mt][nt][r], s1v[nt], t1v[nt]), 0.f);
        aw[k * ATS + nt * 16 + l15] = (ushort_t)bf16b(a);
      }
    }
  // ---- phase 3: gemm2 MFMA (A from actT, B = Bp2), stats per o ----
  f32x4 acc2[2][8];
#pragma unroll
  for (int mt = 0; mt < 2; ++mt)
#pragma unroll
    for (int nt = 0; nt < 8; ++nt) acc2[mt][nt] = (f32x4){0.f, 0.f, 0.f, 0.f};
#pragma unroll
  for (int kc = 0; kc < 4; ++kc) {
    bf16x8 afrag[2];
#pragma unroll
    for (int mt = 0; mt < 2; ++mt)
      afrag[mt] = *(const bf16x8*)(aw + (mt * 16 + l15) * ATS + kc * 32 + r8);
#pragma unroll
    for (int nt = 0; nt < 8; ++nt) {
      bf16x8 bfrag = *(const bf16x8*)(Bp2 + ((nt * 4 + kc) * 64 + lane) * 8);
      acc2[0][nt] = __builtin_amdgcn_mfma_f32_16x16x32_bf16(afrag[0], bfrag, acc2[0][nt], 0, 0, 0);
      acc2[1][nt] = __builtin_amdgcn_mfma_f32_16x16x32_bf16(afrag[1], bfrag, acc2[1][nt], 0, 0, 0);
    }
  }
#pragma unroll
  for (int nt = 0; nt < 8; ++nt) {
    float s = 0.f, q = 0.f, mx = -1e30f, mn = 1e30f;
#pragma unroll
    for (int mt = 0; mt < 2; ++mt)
#pragma unroll
      for (int r = 0; r < 4; ++r) {
        float a = acc2[mt][nt][r];
        s += a; q = fmaf(a, a, q); mx = fmaxf(mx, a); mn = fminf(mn, a);
      }
    s += __shfl_xor(s, 16, 64); s += __shfl_xor(s, 32, 64);
    q += __shfl_xor(q, 16, 64); q += __shfl_xor(q, 32, 64);
    mx = fmaxf(mx, __shfl_xor(mx, 16, 64)); mx = fmaxf(mx, __shfl_xor(mx, 32, 64));
    mn = fminf(mn, __shfl_xor(mn, 16, 64)); mn = fminf(mn, __shfl_xor(mn, 32, 64));
    if (lane < 16) {
      int o = nt * 16 + lane;
      psum[o * G_ + g] = s; psq[o * G_ + g] = q;
      hmax[o * G_ + g] = mx; hmin[o * G_ + g] = mn;
    }
  }
}

// ---------------- pool: out[b,o,s] = relu(s2 * (s2>=0 ? max : min) + t2) ----------------
__global__ __launch_bounds__(256) void pool_kernel(const float* __restrict__ hmax,
    const float* __restrict__ hmin, const float* __restrict__ bnp2,
    float* __restrict__ out) {
  int i = blockIdx.x * 256 + threadIdx.x;   // 1,048,576 = (b*128+o)*512+s
  int s = i & 511;
  int o = (i >> 9) & 127;
  int b = i >> 16;
  int g = b * 512 + s;
  float scv = bnp2[2 * o], tf = bnp2[2 * o + 1];
  float v = (scv >= 0.f) ? hmax[o * G_ + g] : hmin[o * G_ + g];
  out[i] = fmaxf(fmaf(scv, v, tf), 0.f);
}

extern "C" void kernel_launch(void* const* d_in, const int* in_sizes, int n_in,
                              void* d_out, int out_size, void* d_ws, size_t ws_size,
                              hipStream_t stream) {
  const float* x      = (const float*)d_in[0];
  const float* coords = (const float*)d_in[1];
  const float* W1     = (const float*)d_in[2];
  const float* W2     = (const float*)d_in[3];
  const float* gamma1 = (const float*)d_in[4];
  const float* beta1  = (const float*)d_in[5];
  const float* gamma2 = (const float*)d_in[6];
  const float* beta2  = (const float*)d_in[7];
  float* out = (float*)d_out;
  char* ws = (char*)d_ws;
  float* psum1 = (float*)(ws);                    // 4 MB each
  float* psq1  = (float*)(ws + 4194304);
  float* psum2 = (float*)(ws + 8388608);
  float* psq2  = (float*)(ws + 12582912);
  float* hmax  = (float*)(ws + 16777216);
  float* hmin  = (float*)(ws + 20971520);
  ushort_t* xT = (ushort_t*)(ws + 25165824);      // 4 MB  xT[b][n][c] bf16
  ushort_t* Bp1 = (ushort_t*)(ws + 29360128);     // 16 KB
  ushort_t* Bpd = (ushort_t*)(ws + 29376512);     // 16 KB
  ushort_t* Bp2 = (ushort_t*)(ws + 29392896);     // 32 KB
  float* bnp1  = (float*)(ws + 29425664);
  float* bnp2  = (float*)(ws + 29426688);
  int* fidx    = (int*)(ws + 29427712);           // 32 KB
  int* gidx    = (int*)(ws + 29460480);           // 1 MB, end ~30.5 MB

  front_kernel<<<592, 256, 0, stream>>>(coords, x, W1, W2, fidx, out, xT, Bp1, Bpd, Bp2);
  gemm1_kernel<<<2048, 256, 0, stream>>>(xT, coords, fidx, Bp1, Bpd, gidx, psum1, psq1);
  bn_finalize<<<128, 256, 0, stream>>>(psum1, psq1, gamma1, beta1, bnp1);
  gemm2_kernel<<<2048, 256, 0, stream>>>(xT, fidx, gidx, Bp1, Bpd, Bp2, bnp1,
                                         psum2, psq2, hmax, hmin);
  bn_finalize<<<128, 256, 0, stream>>>(psum2, psq2, gamma2, beta2, bnp2);
  pool_kernel<<<4096, 256, 0, stream>>>(hmax, hmin, bnp2, out + 24576);
}